// Round 3
// baseline (278.553 us; speedup 1.0000x reference)
//
#include <hip/hip_runtime.h>

// ISDLoss_only_type1: masked symmetric KL between mixed conf and interpolation.
// B=128, N=8732, C=21; fp32 in, scalar fp32 out.
//
// R2: LDS-staged tiles. 107us main; 65KB LDS -> 8 waves/CU -> latency-bound.
// R3: per-lane register rows. Cache-thrash, FETCH 2.4x inputs, 228us. REVERTED.
// R4: wave-cooperative rows (lane l%21 = class, l/21 = row; coalesced scalar
//     loads; ballot masks + 5-round guarded shfl tree). 110us, VALUBusy 38%,
//     FETCH=once-per-byte. L3-warm dispatch ALSO 106us -> latency-bound on the
//     per-iteration serial chain (load -> 7 dependent bpermutes ~1500cy vs
//     ~100cy issue; 6.2 waves * 104/1600 = 0.40 = measured VALUBusy).
// R5: kill the in-loop shuffle tree -- per-lane masked accumulation makes the
//     row-sum implicit in the global reduction (only the mask needs cross-lane:
//     2 independent bpermute broadcasts + 2 ballots + 21-bit window test).
//     Unroll 4 independent groups per iteration for ILP. Chain/iter drops
//     ~1500cy -> ~400cy with 4x the issuable work per chain.

#define EPS 1e-7f

constexpr int B = 128;
constexpr int N = 8732;
constexpr int C = 21;
constexpr int ROWS = B * N;                  // 1,117,696
constexpr int ELEMS = ROWS * C;              // 23,471,616
constexpr int HALF_ELEMS = (B / 2) * N * C;  // 11,735,808
constexpr int GELEMS = 63;                   // 3 rows per wave-group
constexpr int NGROUPS = (ROWS + 2) / 3;      // 372,566
constexpr int BLOCK = 256;
constexpr int GRID = 2048;                   // 8 blocks/CU
constexpr int NWAVES = GRID * (BLOCK / 64);  // 8192

__global__ __launch_bounds__(BLOCK, 4) void isd_main_kernel(
    const float* __restrict__ lam_p,
    const float* __restrict__ conf,
    const float* __restrict__ csh,   // conf_shuffle
    const float* __restrict__ cin,   // conf_interpolation
    double* __restrict__ partials)   // [2*GRID]: (sum, cnt) per block
{
    const int tid  = threadIdx.x;
    const int lane = tid & 63;
    // wave-uniform wave id -> scalar base addressing inside the loop
    const int wid  = __builtin_amdgcn_readfirstlane(
                         blockIdx.x * (BLOCK / 64) + (tid >> 6));

    const int dr   = lane / 21;          // row within group: 0..2 (lane63 -> 3)
    const int cpos = lane - dr * 21;     // class index 0..20
    const int gb   = dr * 21;            // first lane of my row (63 for lane63)
    const bool lane_ok = lane < GELEMS;

    const float lam = lam_p[0];
    const float oml = 1.0f - lam;

    double bs = 0.0;
    float  bc = 0.0f;                    // exact integer counts (<= ~64)

    auto body = [&](int g) {
        const int  e     = g * GELEMS + lane;
        const bool valid = lane_ok && (e < ELEMS);   // e>=ELEMS covers g>=NGROUPS
        const int  ec    = valid ? e : 0;

        // fully coalesced: 64 lanes x 4B contiguous per load
        const float cv  = conf[ec];
        const float ivr = cin[ec];
        const int   e2  = ec + ((ec < HALF_ELEMS) ? HALF_ELEMS : -HALF_ELEMS);
        const float tv  = csh[e2];

        const float iv = ivr + EPS;
        const float mv = fmaf(lam, cv, oml * tv) + EPS;
        // kl_a + kl_b per class: iv*(li-lm) + mv*(lm-li) == (iv-mv)*(li-lm)
        const float klt = (iv - mv) * (__logf(iv) - __logf(mv));

        // foreground mask: broadcast class-0 of my row, ballot, window test.
        // (cpos==0 lane compares x>x == false -> its own bit is harmlessly 0)
        const float c0 = __shfl(cv, gb, 64);
        const float t0 = __shfl(tv, gb, 64);
        const unsigned long long balc = __ballot(cv > c0);
        const unsigned long long balt = __ballot(tv > t0);
        const bool fg = (((balc >> gb) & 0x1FFFFFull) != 0ull) &&
                        (((balt >> gb) & 0x1FFFFFull) != 0ull);

        const float m = (fg && valid) ? 1.0f : 0.0f;
        bs += (double)(klt * m);             // row-sum happens in global reduce
        bc += (cpos == 0) ? m : 0.0f;        // one count per row
    };

    // 4 independent groups per iteration; tail absorbed by the valid clamp
    for (int g = wid; g < NGROUPS; g += 4 * NWAVES) {
        body(g);
        body(g + 1 * NWAVES);
        body(g + 2 * NWAVES);
        body(g + 3 * NWAVES);
    }

    // ---- reduce: wave shuffle (doubles) -> LDS -> per-block double partial ----
    double bcD = (double)bc;
    #pragma unroll
    for (int off = 32; off > 0; off >>= 1) {
        bs  += __shfl_down(bs,  off, 64);
        bcD += __shfl_down(bcD, off, 64);
    }

    __shared__ double r_sum[BLOCK / 64];
    __shared__ double r_cnt[BLOCK / 64];
    const int wave = tid >> 6;
    if ((tid & 63) == 0) { r_sum[wave] = bs; r_cnt[wave] = bcD; }
    __syncthreads();

    if (tid == 0) {
        double s = 0.0, c = 0.0;
        #pragma unroll
        for (int w = 0; w < BLOCK / 64; ++w) { s += r_sum[w]; c += r_cnt[w]; }
        partials[2 * blockIdx.x + 0] = s;
        partials[2 * blockIdx.x + 1] = c;
    }
}

__global__ __launch_bounds__(256) void isd_final_kernel(
    const double* __restrict__ partials,
    float* __restrict__ out)
{
    double s = 0.0, c = 0.0;
    for (int i = threadIdx.x; i < GRID; i += 256) {
        s += partials[2 * i + 0];
        c += partials[2 * i + 1];
    }
    #pragma unroll
    for (int off = 32; off > 0; off >>= 1) {
        s += __shfl_down(s, off, 64);
        c += __shfl_down(c, off, 64);
    }
    __shared__ double ss[4], sc[4];
    const int wave = threadIdx.x >> 6;
    const int lane = threadIdx.x & 63;
    if (lane == 0) { ss[wave] = s; sc[wave] = c; }
    __syncthreads();
    if (threadIdx.x == 0) {
        const double S  = ss[0] + ss[1] + ss[2] + ss[3];
        const double Cc = sc[0] + sc[1] + sc[2] + sc[3];
        out[0] = (Cc > 0.0) ? (float)(S / fmax(Cc, 1.0) * 0.5) : 0.0f;
    }
}

extern "C" void kernel_launch(void* const* d_in, const int* in_sizes, int n_in,
                              void* d_out, int out_size, void* d_ws, size_t ws_size,
                              hipStream_t stream) {
    const float* lam  = (const float*)d_in[0];
    const float* conf = (const float*)d_in[1];
    const float* csh  = (const float*)d_in[2];
    const float* cin  = (const float*)d_in[3];
    float* out = (float*)d_out;
    double* partials = (double*)d_ws;   // 2*GRID doubles = 32 KB

    isd_main_kernel<<<GRID, BLOCK, 0, stream>>>(lam, conf, csh, cin, partials);
    isd_final_kernel<<<1, 256, 0, stream>>>(partials, out);
}

// Round 4
// 278.015 us; speedup vs baseline: 1.0019x; 1.0019x over previous
//
#include <hip/hip_runtime.h>

// ISDLoss_only_type1: masked symmetric KL between mixed conf and interpolation.
// B=128, N=8732, C=21; fp32 in, scalar fp32 out.
//
// R2: LDS-staged tiles. 107us main; 65KB LDS -> latency-bound at 20% occ.
// R3: per-lane register rows. Cache-thrash, FETCH 2.4x, 228us. REVERTED.
// R4: wave-cooperative rows + ballot masks + shfl tree. 110us, VALUBusy 38%.
//     L3-warm dispatch also ~106us -> latency-bound, not BW-bound.
// R5: tree removed (per-lane masked accumulate), 4x lambda "unroll". 116us,
//     VGPR=28 -> compiler SERIALIZED the bodies: loads cannot hoist across
//     the convergent __shfl/__ballot at each body's end. Little's law: only
//     ~0.3 loads in flight per wave -> request-starved, the real plateau cause.
// R6: phase-split software pipeline. Each iteration: [12 named loads, no
//     convergent ops between] -> [pure VALU for 4 groups] -> [8 independent
//     shfl/ballot + accumulate]. Loads all issue at iteration top (3KB in
//     flight/wave); one chain exposure per 4 groups.

#define EPS 1e-7f

constexpr int B = 128;
constexpr int N = 8732;
constexpr int C = 21;
constexpr int ROWS = B * N;                  // 1,117,696
constexpr int ELEMS = ROWS * C;              // 23,471,616
constexpr int HALF_ELEMS = (B / 2) * N * C;  // 11,735,808
constexpr int GELEMS = 63;                   // 3 rows per wave-group
constexpr int NGROUPS = (ROWS + 2) / 3;      // 372,566
constexpr int BLOCK = 256;
constexpr int GRID = 2048;                   // 8 blocks/CU target
constexpr int NWAVES = GRID * (BLOCK / 64);  // 8192

__global__ __launch_bounds__(BLOCK, 6) void isd_main_kernel(
    const float* __restrict__ lam_p,
    const float* __restrict__ conf,
    const float* __restrict__ csh,   // conf_shuffle
    const float* __restrict__ cin,   // conf_interpolation
    double* __restrict__ partials)   // [2*GRID]: (sum, cnt) per block
{
    const int tid  = threadIdx.x;
    const int lane = tid & 63;
    const int wid  = __builtin_amdgcn_readfirstlane(
                         blockIdx.x * (BLOCK / 64) + (tid >> 6));

    const int dr   = lane / 21;          // row within group: 0..2 (lane63 -> 3)
    const int cpos = lane - dr * 21;     // class index 0..20
    const int gb   = dr * 21;            // first lane of my row (63 for lane63)
    const bool lane_ok = lane < GELEMS;

    const float lam = lam_p[0];
    const float oml = 1.0f - lam;

    double bs = 0.0;
    float  bc = 0.0f;                    // exact small-integer counts

    for (int g = wid; g < NGROUPS; g += 4 * NWAVES) {
        // ---------- phase 1: addresses + 12 loads, no convergent ops ----------
        const int e0 = (g + 0 * NWAVES) * GELEMS + lane;
        const int e1 = (g + 1 * NWAVES) * GELEMS + lane;
        const int e2 = (g + 2 * NWAVES) * GELEMS + lane;
        const int e3 = (g + 3 * NWAVES) * GELEMS + lane;
        const bool v0 = lane_ok && (e0 < ELEMS);
        const bool v1 = lane_ok && (e1 < ELEMS);
        const bool v2 = lane_ok && (e2 < ELEMS);
        const bool v3 = lane_ok && (e3 < ELEMS);
        const int a0 = v0 ? e0 : 0;
        const int a1 = v1 ? e1 : 0;
        const int a2 = v2 ? e2 : 0;
        const int a3 = v3 ? e3 : 0;
        const int f0 = a0 + ((a0 < HALF_ELEMS) ? HALF_ELEMS : -HALF_ELEMS);
        const int f1 = a1 + ((a1 < HALF_ELEMS) ? HALF_ELEMS : -HALF_ELEMS);
        const int f2 = a2 + ((a2 < HALF_ELEMS) ? HALF_ELEMS : -HALF_ELEMS);
        const int f3 = a3 + ((a3 < HALF_ELEMS) ? HALF_ELEMS : -HALF_ELEMS);

        const float cv0 = conf[a0], cv1 = conf[a1], cv2 = conf[a2], cv3 = conf[a3];
        const float in0 = cin[a0],  in1 = cin[a1],  in2 = cin[a2],  in3 = cin[a3];
        const float tv0 = csh[f0],  tv1 = csh[f1],  tv2 = csh[f2],  tv3 = csh[f3];

        // ---------- phase 2: pure VALU ----------
        const float iv0 = in0 + EPS, iv1 = in1 + EPS;
        const float iv2 = in2 + EPS, iv3 = in3 + EPS;
        const float mv0 = fmaf(lam, cv0, oml * tv0) + EPS;
        const float mv1 = fmaf(lam, cv1, oml * tv1) + EPS;
        const float mv2 = fmaf(lam, cv2, oml * tv2) + EPS;
        const float mv3 = fmaf(lam, cv3, oml * tv3) + EPS;
        // kl_a + kl_b per class: iv*(li-lm) + mv*(lm-li) == (iv-mv)*(li-lm)
        const float kl0 = (iv0 - mv0) * (__logf(iv0) - __logf(mv0));
        const float kl1 = (iv1 - mv1) * (__logf(iv1) - __logf(mv1));
        const float kl2 = (iv2 - mv2) * (__logf(iv2) - __logf(mv2));
        const float kl3 = (iv3 - mv3) * (__logf(iv3) - __logf(mv3));

        // ---------- phase 3: convergent ops (all independent) + accumulate ----
        const float c00 = __shfl(cv0, gb, 64);
        const float c01 = __shfl(cv1, gb, 64);
        const float c02 = __shfl(cv2, gb, 64);
        const float c03 = __shfl(cv3, gb, 64);
        const float t00 = __shfl(tv0, gb, 64);
        const float t01 = __shfl(tv1, gb, 64);
        const float t02 = __shfl(tv2, gb, 64);
        const float t03 = __shfl(tv3, gb, 64);
        const unsigned long long bc0 = __ballot(cv0 > c00);
        const unsigned long long bc1 = __ballot(cv1 > c01);
        const unsigned long long bc2 = __ballot(cv2 > c02);
        const unsigned long long bc3 = __ballot(cv3 > c03);
        const unsigned long long bt0 = __ballot(tv0 > t00);
        const unsigned long long bt1 = __ballot(tv1 > t01);
        const unsigned long long bt2 = __ballot(tv2 > t02);
        const unsigned long long bt3 = __ballot(tv3 > t03);

        const unsigned long long M = 0x1FFFFFull;  // 21 bits
        const float m0 = ((((bc0 >> gb) & M) != 0ull) && (((bt0 >> gb) & M) != 0ull) && v0) ? 1.0f : 0.0f;
        const float m1 = ((((bc1 >> gb) & M) != 0ull) && (((bt1 >> gb) & M) != 0ull) && v1) ? 1.0f : 0.0f;
        const float m2 = ((((bc2 >> gb) & M) != 0ull) && (((bt2 >> gb) & M) != 0ull) && v2) ? 1.0f : 0.0f;
        const float m3 = ((((bc3 >> gb) & M) != 0ull) && (((bt3 >> gb) & M) != 0ull) && v3) ? 1.0f : 0.0f;

        bs += (double)(kl0 * m0);
        bs += (double)(kl1 * m1);
        bs += (double)(kl2 * m2);
        bs += (double)(kl3 * m3);
        if (cpos == 0) bc += m0 + m1 + m2 + m3;   // one count per row
    }

    // ---- reduce: wave shuffle (doubles) -> LDS -> per-block double partial ----
    double bcD = (double)bc;
    #pragma unroll
    for (int off = 32; off > 0; off >>= 1) {
        bs  += __shfl_down(bs,  off, 64);
        bcD += __shfl_down(bcD, off, 64);
    }

    __shared__ double r_sum[BLOCK / 64];
    __shared__ double r_cnt[BLOCK / 64];
    const int wave = tid >> 6;
    if ((tid & 63) == 0) { r_sum[wave] = bs; r_cnt[wave] = bcD; }
    __syncthreads();

    if (tid == 0) {
        double s = 0.0, c = 0.0;
        #pragma unroll
        for (int w = 0; w < BLOCK / 64; ++w) { s += r_sum[w]; c += r_cnt[w]; }
        partials[2 * blockIdx.x + 0] = s;
        partials[2 * blockIdx.x + 1] = c;
    }
}

__global__ __launch_bounds__(256) void isd_final_kernel(
    const double* __restrict__ partials,
    float* __restrict__ out)
{
    double s = 0.0, c = 0.0;
    for (int i = threadIdx.x; i < GRID; i += 256) {
        s += partials[2 * i + 0];
        c += partials[2 * i + 1];
    }
    #pragma unroll
    for (int off = 32; off > 0; off >>= 1) {
        s += __shfl_down(s, off, 64);
        c += __shfl_down(c, off, 64);
    }
    __shared__ double ss[4], sc[4];
    const int wave = threadIdx.x >> 6;
    const int lane = threadIdx.x & 63;
    if (lane == 0) { ss[wave] = s; sc[wave] = c; }
    __syncthreads();
    if (threadIdx.x == 0) {
        const double S  = ss[0] + ss[1] + ss[2] + ss[3];
        const double Cc = sc[0] + sc[1] + sc[2] + sc[3];
        out[0] = (Cc > 0.0) ? (float)(S / fmax(Cc, 1.0) * 0.5) : 0.0f;
    }
}

extern "C" void kernel_launch(void* const* d_in, const int* in_sizes, int n_in,
                              void* d_out, int out_size, void* d_ws, size_t ws_size,
                              hipStream_t stream) {
    const float* lam  = (const float*)d_in[0];
    const float* conf = (const float*)d_in[1];
    const float* csh  = (const float*)d_in[2];
    const float* cin  = (const float*)d_in[3];
    float* out = (float*)d_out;
    double* partials = (double*)d_ws;   // 2*GRID doubles = 32 KB

    isd_main_kernel<<<GRID, BLOCK, 0, stream>>>(lam, conf, csh, cin, partials);
    isd_final_kernel<<<1, 256, 0, stream>>>(partials, out);
}

// Round 6
// 277.020 us; speedup vs baseline: 1.0055x; 1.0036x over previous
//
#include <hip/hip_runtime.h>

// ISDLoss_only_type1: masked symmetric KL between mixed conf and interpolation.
// B=128, N=8732, C=21; fp32 in, scalar fp32 out.
//
// R2: LDS-staged tiles. 107us. R3: per-lane f4 rows, cache-thrash, 228us.
// R4: wave-coop scalar loads + ballots. 110us. R5/R6: ILP attempts, 114-116us.
// Cross-round invariant: dur ~110us regardless of occupancy (8 vs 25 w/CU),
// HBM traffic (0 vs 158MB), structure. Per-CU BW stuck at ~10 GB/s = ~12
// outstanding 256B requests -> REQUEST-CONCURRENCY bound, not bytes.
// m13 ubench: dwordx4 copy hits 24.6 GB/s/CU. R3 (the only f4 round) demanded
// >3 TB/s. => bytes-per-request is the lever.
// R7: wave-cooperative float4. Chunk = 252 floats = 12 whole rows; lane l<63
//     owns float4 at 4l -> each load = 1KB contiguous, fully consumed by its
//     own instruction. 2-deep cross-iteration pipeline pinned with
//     sched_barrier(0) (source order alone was defeated in R6). Masks via
//     per-lane precomputed row pattern + 2 ballots/array + lane-range masks.
// R7b: resubmit unchanged -- R7 bench was an infra failure (container died;
//      push_in_npz flake), no kernel verdict. Audit: alignment, bounds,
//      mask lane-ranges, pipeline tail all verified.

#define EPS 1e-7f

constexpr int B = 128;
constexpr int N = 8732;
constexpr int C = 21;
constexpr int ELEMS = B * N * C;              // 23,471,616 (mult of 4)
constexpr int HALF_ELEMS = (B / 2) * N * C;   // 11,735,808 (mult of 4)
constexpr int CHUNK = 252;                    // 12 rows x 21; 63 lanes x float4
constexpr int NCHUNKS = (ELEMS + CHUNK - 1) / CHUNK;  // 93,142
constexpr int BLOCK = 256;
constexpr int GRID = 2048;
constexpr int NWAVES = GRID * (BLOCK / 64);   // 8192
constexpr int KPW = 12;                       // ceil(93142/8192), even

typedef unsigned long long u64;

__global__ __launch_bounds__(BLOCK, 4) void isd_main_kernel(
    const float* __restrict__ lam_p,
    const float* __restrict__ conf,
    const float* __restrict__ csh,   // conf_shuffle
    const float* __restrict__ cin,   // conf_interpolation
    double* __restrict__ partials)   // [2*GRID]: (sum, cnt) per block
{
    const int tid  = threadIdx.x;
    const int lane = tid & 63;
    const int wid  = __builtin_amdgcn_readfirstlane(
                         blockIdx.x * (BLOCK / 64) + (tid >> 6));

    // ---- per-lane constant pattern (chunk layout repeats every 252 elems) ----
    const int  idx0    = 4 * lane;             // 0..252
    const bool lane_ok = (lane < 63);
    const int  r_lo = idx0 / 21;               // row of slot 0
    const int  r_hi = (idx0 + 3) / 21;         // row of slot 3
    const int  r1   = (idx0 + 1) / 21;
    const int  r2   = (idx0 + 2) / 21;
    const bool s1 = (r1 == r_lo), s2 = (r2 == r_lo), s3 = (r_hi == r_lo);
    const bool t0 = (r_lo == r_hi), t1 = (r1 == r_hi), t2 = (r2 == r_hi);
    const int  c0i = idx0 % 21, c1i = (idx0 + 1) % 21,
               c2i = (idx0 + 2) % 21, c3i = (idx0 + 3) % 21;
    const bool nz0 = (c0i != 0), nz1 = (c1i != 0), nz2 = (c2i != 0), nz3 = (c3i != 0);
    const bool hj0 = !nz0, hj1 = !nz1, hj2 = !nz2, hj3 = !nz3;  // head slots
    const int  hl_lo = (21 * r_lo) >> 2;       // lane holding row-head of r_lo
    const int  hl_hi = (21 * r_hi) >> 2;

    // lane-range masks: which ballot bits belong to my rows.
    auto rmask = [](int lo, int hi) -> u64 {
        if (hi > 63) hi = 63;
        if (lo > hi || lo > 63) return 0ull;
        return ((1ull << (hi - lo + 1)) - 1ull) << lo;
    };
    // bl bit at lane l belongs to row (4l)/21; bh bit to row (4l+3)/21.
    const u64 mLL = rmask((21 * r_lo + 3) >> 2, (21 * r_lo + 20) >> 2);
    const u64 mLH = rmask((21 * r_lo) >> 2,     (21 * r_lo + 17) >> 2);
    const u64 mHL = rmask((21 * r_hi + 3) >> 2, (21 * r_hi + 20) >> 2);
    const u64 mHH = rmask((21 * r_hi) >> 2,     (21 * r_hi + 17) >> 2);

    const float lam = lam_p[0];
    const float oml = 1.0f - lam;

    const float4* conf4 = (const float4*)conf;
    const float4* csh4  = (const float4*)csh;
    const float4* cin4  = (const float4*)cin;

    double bs   = 0.0;
    float  cntF = 0.0f;                        // exact small-integer counts

    auto issue = [&](int k, float4& cv4, float4& tv4, float4& iv4) {
        const int  base = (wid + k * NWAVES) * CHUNK;
        const int  e0   = base + idx0;
        const bool vld  = lane_ok && (e0 < ELEMS);
        const int  a    = vld ? e0 : 0;
        const int  f    = a + ((a < HALF_ELEMS) ? HALF_ELEMS : -HALF_ELEMS);
        cv4 = conf4[a >> 2];
        iv4 = cin4 [a >> 2];
        tv4 = csh4 [f >> 2];
    };

    auto compute = [&](int k, const float4& cv4, const float4& tv4, const float4& iv4) {
        const int  e0   = (wid + k * NWAVES) * CHUNK + idx0;
        const bool vld  = lane_ok && (e0 < ELEMS);
        const float vldf = vld ? 1.0f : 0.0f;

        // gather each row's background (class-0) score
        const float headC = hj0 ? cv4.x : (hj1 ? cv4.y : (hj2 ? cv4.z : cv4.w));
        const float headT = hj0 ? tv4.x : (hj1 ? tv4.y : (hj2 ? tv4.z : tv4.w));
        const float c0lo = __shfl(headC, hl_lo, 64);
        const float c0hi = __shfl(headC, hl_hi, 64);
        const float t0lo = __shfl(headT, hl_lo, 64);
        const float t0hi = __shfl(headT, hl_hi, 64);
        const float cb0 = c0lo,                cb1 = s1 ? c0lo : c0hi,
                    cb2 = s2 ? c0lo : c0hi,    cb3 = c0hi;
        const float tb0 = t0lo,                tb1 = s1 ? t0lo : t0hi,
                    tb2 = s2 ? t0lo : t0hi,    tb3 = t0hi;

        // per-slot "foreground candidate" bits (strict >, classes 1..20 only)
        const bool bC0 = vld && nz0 && (cv4.x > cb0);
        const bool bC1 = vld && nz1 && (cv4.y > cb1);
        const bool bC2 = vld && nz2 && (cv4.z > cb2);
        const bool bC3 = vld && nz3 && (cv4.w > cb3);
        const bool bT0 = vld && nz0 && (tv4.x > tb0);
        const bool bT1 = vld && nz1 && (tv4.y > tb1);
        const bool bT2 = vld && nz2 && (tv4.z > tb2);
        const bool bT3 = vld && nz3 && (tv4.w > tb3);

        // fold my slots into lo-row / hi-row contributions, then 4 ballots
        const bool plC = bC0 | (s1 & bC1) | (s2 & bC2) | (s3 & bC3);
        const bool phC = (t0 & bC0) | (t1 & bC1) | (t2 & bC2) | bC3;
        const bool plT = bT0 | (s1 & bT1) | (s2 & bT2) | (s3 & bT3);
        const bool phT = (t0 & bT0) | (t1 & bT1) | (t2 & bT2) | bT3;
        const u64 blC = __ballot(plC);
        const u64 bhC = __ballot(phC);
        const u64 blT = __ballot(plT);
        const u64 bhT = __ballot(phT);

        const bool fgloC = ((blC & mLL) | (bhC & mLH)) != 0ull;
        const bool fghiC = ((blC & mHL) | (bhC & mHH)) != 0ull;
        const bool fgloT = ((blT & mLL) | (bhT & mLH)) != 0ull;
        const bool fghiT = ((blT & mHL) | (bhT & mHH)) != 0ull;
        const float mlo = (fgloC && fgloT) ? 1.0f : 0.0f;
        const float mhi = (fghiC && fghiT) ? 1.0f : 0.0f;
        const float m0 = mlo * vldf,               m1 = (s1 ? mlo : mhi) * vldf,
                    m2 = (s2 ? mlo : mhi) * vldf,  m3 = mhi * vldf;

        // symmetric KL per element: (iv-mv)*(log iv - log mv)
        const float iv0 = iv4.x + EPS, iv1 = iv4.y + EPS,
                    iv2 = iv4.z + EPS, iv3 = iv4.w + EPS;
        const float mv0 = fmaf(lam, cv4.x, oml * tv4.x) + EPS;
        const float mv1 = fmaf(lam, cv4.y, oml * tv4.y) + EPS;
        const float mv2 = fmaf(lam, cv4.z, oml * tv4.z) + EPS;
        const float mv3 = fmaf(lam, cv4.w, oml * tv4.w) + EPS;
        const float kl0 = (iv0 - mv0) * (__logf(iv0) - __logf(mv0));
        const float kl1 = (iv1 - mv1) * (__logf(iv1) - __logf(mv1));
        const float kl2 = (iv2 - mv2) * (__logf(iv2) - __logf(mv2));
        const float kl3 = (iv3 - mv3) * (__logf(iv3) - __logf(mv3));

        bs += (double)(kl0 * m0);
        bs += (double)(kl1 * m1);
        bs += (double)(kl2 * m2);
        bs += (double)(kl3 * m3);
        // one count per row, at its unique head (lane,slot)
        cntF += (hj0 ? m0 : 0.0f) + (hj1 ? m1 : 0.0f)
              + (hj2 ? m2 : 0.0f) + (hj3 ? m3 : 0.0f);
    };

    // ---- 2-deep software pipeline, pinned with sched_barrier ----
    float4 cvA, tvA, ivA, cvB, tvB, ivB;
    issue(0, cvA, tvA, ivA);
    #pragma unroll
    for (int k = 0; k < KPW; k += 2) {
        issue(k + 1, cvB, tvB, ivB);
        __builtin_amdgcn_sched_barrier(0);
        compute(k, cvA, tvA, ivA);
        issue(k + 2, cvA, tvA, ivA);      // k+2==KPW: clamped dummy, harmless
        __builtin_amdgcn_sched_barrier(0);
        compute(k + 1, cvB, tvB, ivB);
    }

    // ---- reduce: wave shuffle (doubles) -> LDS -> per-block double partial ----
    double bcD = (double)cntF;
    #pragma unroll
    for (int off = 32; off > 0; off >>= 1) {
        bs  += __shfl_down(bs,  off, 64);
        bcD += __shfl_down(bcD, off, 64);
    }

    __shared__ double r_sum[BLOCK / 64];
    __shared__ double r_cnt[BLOCK / 64];
    const int wave = tid >> 6;
    if ((tid & 63) == 0) { r_sum[wave] = bs; r_cnt[wave] = bcD; }
    __syncthreads();

    if (tid == 0) {
        double s = 0.0, c = 0.0;
        #pragma unroll
        for (int w = 0; w < BLOCK / 64; ++w) { s += r_sum[w]; c += r_cnt[w]; }
        partials[2 * blockIdx.x + 0] = s;
        partials[2 * blockIdx.x + 1] = c;
    }
}

__global__ __launch_bounds__(256) void isd_final_kernel(
    const double* __restrict__ partials,
    float* __restrict__ out)
{
    double s = 0.0, c = 0.0;
    for (int i = threadIdx.x; i < GRID; i += 256) {
        s += partials[2 * i + 0];
        c += partials[2 * i + 1];
    }
    #pragma unroll
    for (int off = 32; off > 0; off >>= 1) {
        s += __shfl_down(s, off, 64);
        c += __shfl_down(c, off, 64);
    }
    __shared__ double ss[4], sc[4];
    const int wave = threadIdx.x >> 6;
    const int lane = threadIdx.x & 63;
    if (lane == 0) { ss[wave] = s; sc[wave] = c; }
    __syncthreads();
    if (threadIdx.x == 0) {
        const double S  = ss[0] + ss[1] + ss[2] + ss[3];
        const double Cc = sc[0] + sc[1] + sc[2] + sc[3];
        out[0] = (Cc > 0.0) ? (float)(S / fmax(Cc, 1.0) * 0.5) : 0.0f;
    }
}

extern "C" void kernel_launch(void* const* d_in, const int* in_sizes, int n_in,
                              void* d_out, int out_size, void* d_ws, size_t ws_size,
                              hipStream_t stream) {
    const float* lam  = (const float*)d_in[0];
    const float* conf = (const float*)d_in[1];
    const float* csh  = (const float*)d_in[2];
    const float* cin  = (const float*)d_in[3];
    float* out = (float*)d_out;
    double* partials = (double*)d_ws;   // 2*GRID doubles = 32 KB

    isd_main_kernel<<<GRID, BLOCK, 0, stream>>>(lam, conf, csh, cin, partials);
    isd_final_kernel<<<1, 256, 0, stream>>>(partials, out);
}

// Round 9
// 247.890 us; speedup vs baseline: 1.1237x; 1.1175x over previous
//
#include <hip/hip_runtime.h>

// ISDLoss_only_type1: masked symmetric KL between mixed conf and interpolation.
// B=128, N=8732, C=21; fp32 in, scalar fp32 out.
//
// Ledger: R2 LDS-stage 107us | R3 per-lane f4 228us (FETCH 687MB, thrash) |
// R4 wave-coop scalar 110us | R5/R6 ILP variants 114-116us | R7 wave-coop
// float4 + 2-deep sched_barrier pipeline 111-114us.
// Cross-round invariant: demand-side read BW pinned at 2.4-2.7 TB/s across
// ALL structures (occupancy 8-25 w/CU, scalar/vector, LDS/reg, pipelined or
// not); L3-warm dispatch same speed -> limit is the read/fill path above HBM,
// not DRAM, not VALU (22-39%), not concurrency. Even R3 only reached 3.0 TB/s
// at HBM. m13's "6.3 TB/s" copy = 3.15 read + 3.15 write -> read-path ceiling
// ~3 TB/s is consistent with everything observed.
// R8: single-variable test of the last untested lever -- NONTEMPORAL loads
//     (bypass L2/L3 allocation on the fill path). Also: OOB clamp min(e0,
//     ELEMS-4) so lane63 stays request-contiguous (was hammering line 0).
//     If time unchanged -> read ceiling confirmed with 6 structures + nt.
// R8b: compile fix -- __builtin_nontemporal_load requires a NATIVE vector
//      type (clang ext_vector_type), not HIP_vector_type<float,4>.
// R8c: resubmit unchanged -- Round 8 was an infra failure (container died;
//      same flake as Round 5, which passed on identical resubmit). Kernel
//      audited: bounds clamped, no spins, legal nt-load form.

#define EPS 1e-7f

constexpr int B = 128;
constexpr int N = 8732;
constexpr int C = 21;
constexpr int ELEMS = B * N * C;              // 23,471,616 (mult of 4)
constexpr int HALF_ELEMS = (B / 2) * N * C;   // 11,735,808 (mult of 4)
constexpr int CHUNK = 252;                    // 12 rows x 21; 63 lanes x float4
constexpr int NCHUNKS = (ELEMS + CHUNK - 1) / CHUNK;  // 93,142 (last partial)
constexpr int BLOCK = 256;
constexpr int GRID = 2048;
constexpr int NWAVES = GRID * (BLOCK / 64);   // 8192
constexpr int KPW = 12;                       // ceil(93142/8192), even

typedef unsigned long long u64;
typedef float nf4 __attribute__((ext_vector_type(4)));   // native vec for nt-load

__global__ __launch_bounds__(BLOCK, 4) void isd_main_kernel(
    const float* __restrict__ lam_p,
    const float* __restrict__ conf,
    const float* __restrict__ csh,   // conf_shuffle
    const float* __restrict__ cin,   // conf_interpolation
    double* __restrict__ partials)   // [2*GRID]: (sum, cnt) per block
{
    const int tid  = threadIdx.x;
    const int lane = tid & 63;
    const int wid  = __builtin_amdgcn_readfirstlane(
                         blockIdx.x * (BLOCK / 64) + (tid >> 6));

    // ---- per-lane constant pattern (chunk layout repeats every 252 elems) ----
    const int  idx0    = 4 * lane;             // 0..252
    const bool lane_ok = (lane < 63);
    const int  r_lo = idx0 / 21;               // row of slot 0
    const int  r_hi = (idx0 + 3) / 21;         // row of slot 3
    const int  r1   = (idx0 + 1) / 21;
    const int  r2   = (idx0 + 2) / 21;
    const bool s1 = (r1 == r_lo), s2 = (r2 == r_lo), s3 = (r_hi == r_lo);
    const bool t0 = (r_lo == r_hi), t1 = (r1 == r_hi), t2 = (r2 == r_hi);
    const int  c0i = idx0 % 21, c1i = (idx0 + 1) % 21,
               c2i = (idx0 + 2) % 21, c3i = (idx0 + 3) % 21;
    const bool nz0 = (c0i != 0), nz1 = (c1i != 0), nz2 = (c2i != 0), nz3 = (c3i != 0);
    const bool hj0 = !nz0, hj1 = !nz1, hj2 = !nz2, hj3 = !nz3;  // head slots
    const int  hl_lo = (21 * r_lo) >> 2;       // lane holding row-head of r_lo
    const int  hl_hi = (21 * r_hi) >> 2;

    // lane-range masks: which ballot bits belong to my rows.
    auto rmask = [](int lo, int hi) -> u64 {
        if (hi > 63) hi = 63;
        if (lo > hi || lo > 63) return 0ull;
        return ((1ull << (hi - lo + 1)) - 1ull) << lo;
    };
    // bl bit at lane l belongs to row (4l)/21; bh bit to row (4l+3)/21.
    const u64 mLL = rmask((21 * r_lo + 3) >> 2, (21 * r_lo + 20) >> 2);
    const u64 mLH = rmask((21 * r_lo) >> 2,     (21 * r_lo + 17) >> 2);
    const u64 mHL = rmask((21 * r_hi + 3) >> 2, (21 * r_hi + 20) >> 2);
    const u64 mHH = rmask((21 * r_hi) >> 2,     (21 * r_hi + 17) >> 2);

    const float lam = lam_p[0];
    const float oml = 1.0f - lam;

    const nf4* conf4 = (const nf4*)conf;
    const nf4* csh4  = (const nf4*)csh;
    const nf4* cin4  = (const nf4*)cin;

    double bs   = 0.0;
    float  cntF = 0.0f;                        // exact small-integer counts

    auto issue = [&](int k, nf4& cv4, nf4& tv4, nf4& iv4) {
        const int base = (wid + k * NWAVES) * CHUNK;
        int e0 = base + idx0;
        // clamp keeps OOB lanes in-bounds AND contiguous with the wave's
        // request (lane63 of a valid chunk reads the next chunk's first f4)
        e0 = (e0 < ELEMS - 4) ? e0 : (ELEMS - 4);
        const int f = e0 + ((e0 < HALF_ELEMS) ? HALF_ELEMS : -HALF_ELEMS);
        cv4 = __builtin_nontemporal_load(&conf4[e0 >> 2]);
        iv4 = __builtin_nontemporal_load(&cin4 [e0 >> 2]);
        tv4 = __builtin_nontemporal_load(&csh4 [f  >> 2]);
    };

    auto compute = [&](int k, const nf4& cv4, const nf4& tv4, const nf4& iv4) {
        const int  e0   = (wid + k * NWAVES) * CHUNK + idx0;
        const bool vld  = lane_ok && (e0 < ELEMS);
        const float vldf = vld ? 1.0f : 0.0f;

        // gather each row's background (class-0) score
        const float headC = hj0 ? cv4.x : (hj1 ? cv4.y : (hj2 ? cv4.z : cv4.w));
        const float headT = hj0 ? tv4.x : (hj1 ? tv4.y : (hj2 ? tv4.z : tv4.w));
        const float c0lo = __shfl(headC, hl_lo, 64);
        const float c0hi = __shfl(headC, hl_hi, 64);
        const float t0lo = __shfl(headT, hl_lo, 64);
        const float t0hi = __shfl(headT, hl_hi, 64);
        const float cb0 = c0lo,                cb1 = s1 ? c0lo : c0hi,
                    cb2 = s2 ? c0lo : c0hi,    cb3 = c0hi;
        const float tb0 = t0lo,                tb1 = s1 ? t0lo : t0hi,
                    tb2 = s2 ? t0lo : t0hi,    tb3 = t0hi;

        // per-slot "foreground candidate" bits (strict >, classes 1..20 only)
        const bool bC0 = vld && nz0 && (cv4.x > cb0);
        const bool bC1 = vld && nz1 && (cv4.y > cb1);
        const bool bC2 = vld && nz2 && (cv4.z > cb2);
        const bool bC3 = vld && nz3 && (cv4.w > cb3);
        const bool bT0 = vld && nz0 && (tv4.x > tb0);
        const bool bT1 = vld && nz1 && (tv4.y > tb1);
        const bool bT2 = vld && nz2 && (tv4.z > tb2);
        const bool bT3 = vld && nz3 && (tv4.w > tb3);

        // fold my slots into lo-row / hi-row contributions, then 4 ballots
        const bool plC = bC0 | (s1 & bC1) | (s2 & bC2) | (s3 & bC3);
        const bool phC = (t0 & bC0) | (t1 & bC1) | (t2 & bC2) | bC3;
        const bool plT = bT0 | (s1 & bT1) | (s2 & bT2) | (s3 & bT3);
        const bool phT = (t0 & bT0) | (t1 & bT1) | (t2 & bT2) | bT3;
        const u64 blC = __ballot(plC);
        const u64 bhC = __ballot(phC);
        const u64 blT = __ballot(plT);
        const u64 bhT = __ballot(phT);

        const bool fgloC = ((blC & mLL) | (bhC & mLH)) != 0ull;
        const bool fghiC = ((blC & mHL) | (bhC & mHH)) != 0ull;
        const bool fgloT = ((blT & mLL) | (bhT & mLH)) != 0ull;
        const bool fghiT = ((blT & mHL) | (bhT & mHH)) != 0ull;
        const float mlo = (fgloC && fgloT) ? 1.0f : 0.0f;
        const float mhi = (fghiC && fghiT) ? 1.0f : 0.0f;
        const float m0 = mlo * vldf,               m1 = (s1 ? mlo : mhi) * vldf,
                    m2 = (s2 ? mlo : mhi) * vldf,  m3 = mhi * vldf;

        // symmetric KL per element: (iv-mv)*(log iv - log mv)
        const float iv0 = iv4.x + EPS, iv1 = iv4.y + EPS,
                    iv2 = iv4.z + EPS, iv3 = iv4.w + EPS;
        const float mv0 = fmaf(lam, cv4.x, oml * tv4.x) + EPS;
        const float mv1 = fmaf(lam, cv4.y, oml * tv4.y) + EPS;
        const float mv2 = fmaf(lam, cv4.z, oml * tv4.z) + EPS;
        const float mv3 = fmaf(lam, cv4.w, oml * tv4.w) + EPS;
        const float kl0 = (iv0 - mv0) * (__logf(iv0) - __logf(mv0));
        const float kl1 = (iv1 - mv1) * (__logf(iv1) - __logf(mv1));
        const float kl2 = (iv2 - mv2) * (__logf(iv2) - __logf(mv2));
        const float kl3 = (iv3 - mv3) * (__logf(iv3) - __logf(mv3));

        bs += (double)(kl0 * m0);
        bs += (double)(kl1 * m1);
        bs += (double)(kl2 * m2);
        bs += (double)(kl3 * m3);
        // one count per row, at its unique head (lane,slot)
        cntF += (hj0 ? m0 : 0.0f) + (hj1 ? m1 : 0.0f)
              + (hj2 ? m2 : 0.0f) + (hj3 ? m3 : 0.0f);
    };

    // ---- 2-deep software pipeline, pinned with sched_barrier ----
    nf4 cvA, tvA, ivA, cvB, tvB, ivB;
    issue(0, cvA, tvA, ivA);
    #pragma unroll
    for (int k = 0; k < KPW; k += 2) {
        issue(k + 1, cvB, tvB, ivB);
        __builtin_amdgcn_sched_barrier(0);
        compute(k, cvA, tvA, ivA);
        issue(k + 2, cvA, tvA, ivA);      // k+2==KPW: clamped dummy, harmless
        __builtin_amdgcn_sched_barrier(0);
        compute(k + 1, cvB, tvB, ivB);
    }

    // ---- reduce: wave shuffle (doubles) -> LDS -> per-block double partial ----
    double bcD = (double)cntF;
    #pragma unroll
    for (int off = 32; off > 0; off >>= 1) {
        bs  += __shfl_down(bs,  off, 64);
        bcD += __shfl_down(bcD, off, 64);
    }

    __shared__ double r_sum[BLOCK / 64];
    __shared__ double r_cnt[BLOCK / 64];
    const int wave = tid >> 6;
    if ((tid & 63) == 0) { r_sum[wave] = bs; r_cnt[wave] = bcD; }
    __syncthreads();

    if (tid == 0) {
        double s = 0.0, c = 0.0;
        #pragma unroll
        for (int w = 0; w < BLOCK / 64; ++w) { s += r_sum[w]; c += r_cnt[w]; }
        partials[2 * blockIdx.x + 0] = s;
        partials[2 * blockIdx.x + 1] = c;
    }
}

__global__ __launch_bounds__(256) void isd_final_kernel(
    const double* __restrict__ partials,
    float* __restrict__ out)
{
    double s = 0.0, c = 0.0;
    for (int i = threadIdx.x; i < GRID; i += 256) {
        s += partials[2 * i + 0];
        c += partials[2 * i + 1];
    }
    #pragma unroll
    for (int off = 32; off > 0; off >>= 1) {
        s += __shfl_down(s, off, 64);
        c += __shfl_down(c, off, 64);
    }
    __shared__ double ss[4], sc[4];
    const int wave = threadIdx.x >> 6;
    const int lane = threadIdx.x & 63;
    if (lane == 0) { ss[wave] = s; sc[wave] = c; }
    __syncthreads();
    if (threadIdx.x == 0) {
        const double S  = ss[0] + ss[1] + ss[2] + ss[3];
        const double Cc = sc[0] + sc[1] + sc[2] + sc[3];
        out[0] = (Cc > 0.0) ? (float)(S / fmax(Cc, 1.0) * 0.5) : 0.0f;
    }
}

extern "C" void kernel_launch(void* const* d_in, const int* in_sizes, int n_in,
                              void* d_out, int out_size, void* d_ws, size_t ws_size,
                              hipStream_t stream) {
    const float* lam  = (const float*)d_in[0];
    const float* conf = (const float*)d_in[1];
    const float* csh  = (const float*)d_in[2];
    const float* cin  = (const float*)d_in[3];
    float* out = (float*)d_out;
    double* partials = (double*)d_ws;   // 2*GRID doubles = 32 KB

    isd_main_kernel<<<GRID, BLOCK, 0, stream>>>(lam, conf, csh, cin, partials);
    isd_final_kernel<<<1, 256, 0, stream>>>(partials, out);
}

// Round 10
// 247.667 us; speedup vs baseline: 1.1247x; 1.0009x over previous
//
#include <hip/hip_runtime.h>

// ISDLoss_only_type1: masked symmetric KL between mixed conf and interpolation.
// B=128, N=8732, C=21; fp32 in, scalar fp32 out.
//
// Ledger: R2 LDS-stage 107us | R3 per-lane f4 228us (thrash) | R4 wave-coop
// scalar 110us | R5/R6 ILP 114-116us | R7 wave-coop f4 + 2-deep pipeline
// 111-114us | R8 + NONTEMPORAL loads -> 57.5us (2x!). nt bypasses L2/L3
// allocation on the fill path; the 6-round "2.5 TB/s read ceiling" was
// allocation pressure, not fabric. Demand read now 4.9 TB/s, VALUBusy 67%.
// Harness budget: ~171us of the 248us total is fillBufferAligned re-poison
// (3x 375MB @ 6.6 TB/s) -- fixed. Controllable: main 57.5 + final ~10.
// R10: single-variable -- pipeline depth 2 -> 3 (9 nt-loads, 4.5KB in flight
//      per wave; counted vmcnt(6) before each compute). nt-loads skip L2
//      alloc so effective latency is longer; depth 2 under-covers it.

#define EPS 1e-7f

constexpr int B = 128;
constexpr int N = 8732;
constexpr int C = 21;
constexpr int ELEMS = B * N * C;              // 23,471,616 (mult of 4)
constexpr int HALF_ELEMS = (B / 2) * N * C;   // 11,735,808 (mult of 4)
constexpr int CHUNK = 252;                    // 12 rows x 21; 63 lanes x float4
constexpr int NCHUNKS = (ELEMS + CHUNK - 1) / CHUNK;  // 93,142 (last partial)
constexpr int BLOCK = 256;
constexpr int GRID = 2048;
constexpr int NWAVES = GRID * (BLOCK / 64);   // 8192
constexpr int KPW = 12;                       // ceil(93142/8192), mult of 3? no:
                                              // 12 = 4 iterations of 3 -> ok

typedef unsigned long long u64;
typedef float nf4 __attribute__((ext_vector_type(4)));   // native vec for nt-load

__global__ __launch_bounds__(BLOCK, 4) void isd_main_kernel(
    const float* __restrict__ lam_p,
    const float* __restrict__ conf,
    const float* __restrict__ csh,   // conf_shuffle
    const float* __restrict__ cin,   // conf_interpolation
    double* __restrict__ partials)   // [2*GRID]: (sum, cnt) per block
{
    const int tid  = threadIdx.x;
    const int lane = tid & 63;
    const int wid  = __builtin_amdgcn_readfirstlane(
                         blockIdx.x * (BLOCK / 64) + (tid >> 6));

    // ---- per-lane constant pattern (chunk layout repeats every 252 elems) ----
    const int  idx0    = 4 * lane;             // 0..252
    const bool lane_ok = (lane < 63);
    const int  r_lo = idx0 / 21;               // row of slot 0
    const int  r_hi = (idx0 + 3) / 21;         // row of slot 3
    const int  r1   = (idx0 + 1) / 21;
    const int  r2   = (idx0 + 2) / 21;
    const bool s1 = (r1 == r_lo), s2 = (r2 == r_lo), s3 = (r_hi == r_lo);
    const bool t0 = (r_lo == r_hi), t1 = (r1 == r_hi), t2 = (r2 == r_hi);
    const int  c0i = idx0 % 21, c1i = (idx0 + 1) % 21,
               c2i = (idx0 + 2) % 21, c3i = (idx0 + 3) % 21;
    const bool nz0 = (c0i != 0), nz1 = (c1i != 0), nz2 = (c2i != 0), nz3 = (c3i != 0);
    const bool hj0 = !nz0, hj1 = !nz1, hj2 = !nz2, hj3 = !nz3;  // head slots
    const int  hl_lo = (21 * r_lo) >> 2;       // lane holding row-head of r_lo
    const int  hl_hi = (21 * r_hi) >> 2;

    // lane-range masks: which ballot bits belong to my rows.
    auto rmask = [](int lo, int hi) -> u64 {
        if (hi > 63) hi = 63;
        if (lo > hi || lo > 63) return 0ull;
        return ((1ull << (hi - lo + 1)) - 1ull) << lo;
    };
    // bl bit at lane l belongs to row (4l)/21; bh bit to row (4l+3)/21.
    const u64 mLL = rmask((21 * r_lo + 3) >> 2, (21 * r_lo + 20) >> 2);
    const u64 mLH = rmask((21 * r_lo) >> 2,     (21 * r_lo + 17) >> 2);
    const u64 mHL = rmask((21 * r_hi + 3) >> 2, (21 * r_hi + 20) >> 2);
    const u64 mHH = rmask((21 * r_hi) >> 2,     (21 * r_hi + 17) >> 2);

    const float lam = lam_p[0];
    const float oml = 1.0f - lam;

    const nf4* conf4 = (const nf4*)conf;
    const nf4* csh4  = (const nf4*)csh;
    const nf4* cin4  = (const nf4*)cin;

    double bs   = 0.0;
    float  cntF = 0.0f;                        // exact small-integer counts

    auto issue = [&](int k, nf4& cv4, nf4& tv4, nf4& iv4) {
        const int base = (wid + k * NWAVES) * CHUNK;
        int e0 = base + idx0;
        // clamp keeps OOB lanes in-bounds AND contiguous with the wave's
        // request (lane63 of a valid chunk reads the next chunk's first f4)
        e0 = (e0 < ELEMS - 4) ? e0 : (ELEMS - 4);
        const int f = e0 + ((e0 < HALF_ELEMS) ? HALF_ELEMS : -HALF_ELEMS);
        cv4 = __builtin_nontemporal_load(&conf4[e0 >> 2]);
        iv4 = __builtin_nontemporal_load(&cin4 [e0 >> 2]);
        tv4 = __builtin_nontemporal_load(&csh4 [f  >> 2]);
    };

    auto compute = [&](int k, const nf4& cv4, const nf4& tv4, const nf4& iv4) {
        const int  e0   = (wid + k * NWAVES) * CHUNK + idx0;
        const bool vld  = lane_ok && (e0 < ELEMS);
        const float vldf = vld ? 1.0f : 0.0f;

        // gather each row's background (class-0) score
        const float headC = hj0 ? cv4.x : (hj1 ? cv4.y : (hj2 ? cv4.z : cv4.w));
        const float headT = hj0 ? tv4.x : (hj1 ? tv4.y : (hj2 ? tv4.z : tv4.w));
        const float c0lo = __shfl(headC, hl_lo, 64);
        const float c0hi = __shfl(headC, hl_hi, 64);
        const float t0lo = __shfl(headT, hl_lo, 64);
        const float t0hi = __shfl(headT, hl_hi, 64);
        const float cb0 = c0lo,                cb1 = s1 ? c0lo : c0hi,
                    cb2 = s2 ? c0lo : c0hi,    cb3 = c0hi;
        const float tb0 = t0lo,                tb1 = s1 ? t0lo : t0hi,
                    tb2 = s2 ? t0lo : t0hi,    tb3 = t0hi;

        // per-slot "foreground candidate" bits (strict >, classes 1..20 only)
        const bool bC0 = vld && nz0 && (cv4.x > cb0);
        const bool bC1 = vld && nz1 && (cv4.y > cb1);
        const bool bC2 = vld && nz2 && (cv4.z > cb2);
        const bool bC3 = vld && nz3 && (cv4.w > cb3);
        const bool bT0 = vld && nz0 && (tv4.x > tb0);
        const bool bT1 = vld && nz1 && (tv4.y > tb1);
        const bool bT2 = vld && nz2 && (tv4.z > tb2);
        const bool bT3 = vld && nz3 && (tv4.w > tb3);

        // fold my slots into lo-row / hi-row contributions, then 4 ballots
        const bool plC = bC0 | (s1 & bC1) | (s2 & bC2) | (s3 & bC3);
        const bool phC = (t0 & bC0) | (t1 & bC1) | (t2 & bC2) | bC3;
        const bool plT = bT0 | (s1 & bT1) | (s2 & bT2) | (s3 & bT3);
        const bool phT = (t0 & bT0) | (t1 & bT1) | (t2 & bT2) | bT3;
        const u64 blC = __ballot(plC);
        const u64 bhC = __ballot(phC);
        const u64 blT = __ballot(plT);
        const u64 bhT = __ballot(phT);

        const bool fgloC = ((blC & mLL) | (bhC & mLH)) != 0ull;
        const bool fghiC = ((blC & mHL) | (bhC & mHH)) != 0ull;
        const bool fgloT = ((blT & mLL) | (bhT & mLH)) != 0ull;
        const bool fghiT = ((blT & mHL) | (bhT & mHH)) != 0ull;
        const float mlo = (fgloC && fgloT) ? 1.0f : 0.0f;
        const float mhi = (fghiC && fghiT) ? 1.0f : 0.0f;
        const float m0 = mlo * vldf,               m1 = (s1 ? mlo : mhi) * vldf,
                    m2 = (s2 ? mlo : mhi) * vldf,  m3 = mhi * vldf;

        // symmetric KL per element: (iv-mv)*(log iv - log mv)
        const float iv0 = iv4.x + EPS, iv1 = iv4.y + EPS,
                    iv2 = iv4.z + EPS, iv3 = iv4.w + EPS;
        const float mv0 = fmaf(lam, cv4.x, oml * tv4.x) + EPS;
        const float mv1 = fmaf(lam, cv4.y, oml * tv4.y) + EPS;
        const float mv2 = fmaf(lam, cv4.z, oml * tv4.z) + EPS;
        const float mv3 = fmaf(lam, cv4.w, oml * tv4.w) + EPS;
        const float kl0 = (iv0 - mv0) * (__logf(iv0) - __logf(mv0));
        const float kl1 = (iv1 - mv1) * (__logf(iv1) - __logf(mv1));
        const float kl2 = (iv2 - mv2) * (__logf(iv2) - __logf(mv2));
        const float kl3 = (iv3 - mv3) * (__logf(iv3) - __logf(mv3));

        bs += (double)(kl0 * m0);
        bs += (double)(kl1 * m1);
        bs += (double)(kl2 * m2);
        bs += (double)(kl3 * m3);
        // one count per row, at its unique head (lane,slot)
        cntF += (hj0 ? m0 : 0.0f) + (hj1 ? m1 : 0.0f)
              + (hj2 ? m2 : 0.0f) + (hj3 ? m3 : 0.0f);
    };

    // ---- 3-deep software pipeline, pinned with sched_barrier ----
    nf4 cvA, tvA, ivA, cvB, tvB, ivB, cvC, tvC, ivC;
    issue(0, cvA, tvA, ivA);
    issue(1, cvB, tvB, ivB);
    issue(2, cvC, tvC, ivC);
    #pragma unroll
    for (int k = 0; k < KPW; k += 3) {
        __builtin_amdgcn_sched_barrier(0);
        compute(k, cvA, tvA, ivA);
        issue(k + 3, cvA, tvA, ivA);      // k+3>=KPW: clamped dummy, harmless
        __builtin_amdgcn_sched_barrier(0);
        compute(k + 1, cvB, tvB, ivB);
        issue(k + 4, cvB, tvB, ivB);
        __builtin_amdgcn_sched_barrier(0);
        compute(k + 2, cvC, tvC, ivC);
        issue(k + 5, cvC, tvC, ivC);
    }

    // ---- reduce: wave shuffle (doubles) -> LDS -> per-block double partial ----
    double bcD = (double)cntF;
    #pragma unroll
    for (int off = 32; off > 0; off >>= 1) {
        bs  += __shfl_down(bs,  off, 64);
        bcD += __shfl_down(bcD, off, 64);
    }

    __shared__ double r_sum[BLOCK / 64];
    __shared__ double r_cnt[BLOCK / 64];
    const int wave = tid >> 6;
    if ((tid & 63) == 0) { r_sum[wave] = bs; r_cnt[wave] = bcD; }
    __syncthreads();

    if (tid == 0) {
        double s = 0.0, c = 0.0;
        #pragma unroll
        for (int w = 0; w < BLOCK / 64; ++w) { s += r_sum[w]; c += r_cnt[w]; }
        partials[2 * blockIdx.x + 0] = s;
        partials[2 * blockIdx.x + 1] = c;
    }
}

__global__ __launch_bounds__(256) void isd_final_kernel(
    const double* __restrict__ partials,
    float* __restrict__ out)
{
    double s = 0.0, c = 0.0;
    for (int i = threadIdx.x; i < GRID; i += 256) {
        s += partials[2 * i + 0];
        c += partials[2 * i + 1];
    }
    #pragma unroll
    for (int off = 32; off > 0; off >>= 1) {
        s += __shfl_down(s, off, 64);
        c += __shfl_down(c, off, 64);
    }
    __shared__ double ss[4], sc[4];
    const int wave = threadIdx.x >> 6;
    const int lane = threadIdx.x & 63;
    if (lane == 0) { ss[wave] = s; sc[wave] = c; }
    __syncthreads();
    if (threadIdx.x == 0) {
        const double S  = ss[0] + ss[1] + ss[2] + ss[3];
        const double Cc = sc[0] + sc[1] + sc[2] + sc[3];
        out[0] = (Cc > 0.0) ? (float)(S / fmax(Cc, 1.0) * 0.5) : 0.0f;
    }
}

extern "C" void kernel_launch(void* const* d_in, const int* in_sizes, int n_in,
                              void* d_out, int out_size, void* d_ws, size_t ws_size,
                              hipStream_t stream) {
    const float* lam  = (const float*)d_in[0];
    const float* conf = (const float*)d_in[1];
    const float* csh  = (const float*)d_in[2];
    const float* cin  = (const float*)d_in[3];
    float* out = (float*)d_out;
    double* partials = (double*)d_ws;   // 2*GRID doubles = 32 KB

    isd_main_kernel<<<GRID, BLOCK, 0, stream>>>(lam, conf, csh, cin, partials);
    isd_final_kernel<<<1, 256, 0, stream>>>(partials, out);
}